// Round 2
// baseline (78.446 us; speedup 1.0000x reference)
//
#include <hip/hip_runtime.h>

#define SEQ 512

// Kernel 1: analytic quantum feature + attention per (b,h) pair.
// Q[s][0] = prod_{w=1..7} cos(x_w + th_w);  Q[s][k] = prod_{w=0..k} cos(...)
// grid: (64 pairs, 8 row-chunks), block 256 = 4 waves (j-slices) x 64 lanes (rows)
__global__ __launch_bounds__(256) void qattn_kernel(
    const float* __restrict__ x,      // fp32 [8,512,64]
    const float* __restrict__ theta,  // fp32 [8]
    float* __restrict__ ctx)          // fp32 [8,512,8,8]  (b,s,h,d)
{
    __shared__ float Qs[SEQ][8];      // 16 KB
    __shared__ float red[4][64][9];   // 9.2 KB, stride-9 => conflict-free

    const int pair  = blockIdx.x;     // b*8 + h
    const int chunk = blockIdx.y;     // 0..7
    const int b = pair >> 3, h = pair & 7;
    const int tid = threadIdx.x;

    float th[8];
    #pragma unroll
    for (int w = 0; w < 8; w++) th[w] = theta[w];

    // Build Q for this pair (512 token rows)
    for (int s = tid; s < SEQ; s += 256) {
        const float* xp = x + ((size_t)(b * SEQ + s) * 64 + h * 8);
        float4 xa = *reinterpret_cast<const float4*>(xp);
        float4 xb = *reinterpret_cast<const float4*>(xp + 4);
        float c[8];
        c[0] = __cosf(xa.x + th[0]); c[1] = __cosf(xa.y + th[1]);
        c[2] = __cosf(xa.z + th[2]); c[3] = __cosf(xa.w + th[3]);
        c[4] = __cosf(xb.x + th[4]); c[5] = __cosf(xb.y + th[5]);
        c[6] = __cosf(xb.z + th[6]); c[7] = __cosf(xb.w + th[7]);
        float q[8];
        float pre = c[0];
        #pragma unroll
        for (int k = 1; k < 8; k++) { pre *= c[k]; q[k] = pre; }
        float suf = 1.f;
        #pragma unroll
        for (int w = 7; w >= 1; w--) suf *= c[w];
        q[0] = suf;
        #pragma unroll
        for (int d = 0; d < 8; d++) Qs[s][d] = q[d];
    }
    __syncthreads();

    const int lane  = tid & 63;
    const int slice = tid >> 6;          // wave index == j-slice
    const int r = chunk * 64 + lane;     // this lane's row

    float qr[8];
    #pragma unroll
    for (int d = 0; d < 8; d++) qr[d] = Qs[r][d];

    const float scale = 0.35355339059327373f;  // 1/sqrt(8)
    float acc[8] = {0.f,0.f,0.f,0.f,0.f,0.f,0.f,0.f};
    float l = 0.f;

    // |score*scale| <= sqrt(8): softmax without max-subtraction is safe
    const int j0 = slice * 128;
    #pragma unroll 4
    for (int j = j0; j < j0 + 128; j++) {
        float4 qa = *reinterpret_cast<const float4*>(&Qs[j][0]);  // wave-uniform broadcast
        float4 qb = *reinterpret_cast<const float4*>(&Qs[j][4]);
        float sc = qr[0]*qa.x + qr[1]*qa.y + qr[2]*qa.z + qr[3]*qa.w
                 + qr[4]*qb.x + qr[5]*qb.y + qr[6]*qb.z + qr[7]*qb.w;
        float e = __expf(sc * scale);
        l += e;
        acc[0] += e*qa.x; acc[1] += e*qa.y; acc[2] += e*qa.z; acc[3] += e*qa.w;
        acc[4] += e*qb.x; acc[5] += e*qb.y; acc[6] += e*qb.z; acc[7] += e*qb.w;
    }

    #pragma unroll
    for (int d = 0; d < 8; d++) red[slice][lane][d] = acc[d];
    red[slice][lane][8] = l;
    __syncthreads();

    if (slice == 0) {
        #pragma unroll
        for (int d = 0; d < 8; d++)
            acc[d] = red[0][lane][d] + red[1][lane][d] + red[2][lane][d] + red[3][lane][d];
        l = red[0][lane][8] + red[1][lane][8] + red[2][lane][8] + red[3][lane][8];
        float inv = 1.f / l;
        float* op = ctx + (((size_t)(b * SEQ + r)) * 8 + h) * 8;
        #pragma unroll
        for (int d = 0; d < 8; d++) op[d] = acc[d] * inv;
    }
}

// Kernel 2: out[token, e] = ctx[token, :] . W_o[e, :] + b_o[e]
// grid: 1024 blocks x 256 threads; one thread per output element
__global__ __launch_bounds__(256) void proj_kernel(
    const float* __restrict__ ctx,    // fp32 [4096][64]
    const float* __restrict__ Wo,     // fp32 [64][64]
    const float* __restrict__ bo,     // fp32 [64]
    float* __restrict__ out)          // fp32 [4096][64]
{
    __shared__ float Ws[64][65];      // +1 pad: conflict-free row reads
    const int tid = threadIdx.x;
    for (int idx = tid; idx < 4096; idx += 256) {
        Ws[idx >> 6][idx & 63] = Wo[idx];
    }
    __syncthreads();

    const int g = blockIdx.x * 256 + tid;
    const int token = g >> 6, e = g & 63;

    const float4* cp = reinterpret_cast<const float4*>(ctx + (size_t)token * 64);
    float acc = 0.f;
    #pragma unroll
    for (int k4 = 0; k4 < 16; k4++) {
        float4 c4 = cp[k4];           // wave-uniform broadcast (same token per wave)
        acc += c4.x * Ws[e][k4*4+0] + c4.y * Ws[e][k4*4+1]
             + c4.z * Ws[e][k4*4+2] + c4.w * Ws[e][k4*4+3];
    }
    acc += bo[e];
    out[g] = acc;
}

extern "C" void kernel_launch(void* const* d_in, const int* in_sizes, int n_in,
                              void* d_out, int out_size, void* d_ws, size_t ws_size,
                              hipStream_t stream) {
    const float* x     = (const float*)d_in[0];  // [8,512,64]
    const float* theta = (const float*)d_in[1];  // [8]
    const float* Wo    = (const float*)d_in[2];  // [64,64]
    const float* bo    = (const float*)d_in[3];  // [64]
    float* out = (float*)d_out;                  // [8,512,64]
    float* ctx = (float*)d_ws;                   // 1 MB fp32 scratch

    qattn_kernel<<<dim3(64, 8), 256, 0, stream>>>(x, theta, ctx);
    proj_kernel<<<1024, 256, 0, stream>>>(ctx, Wo, bo, out);
}

// Round 3
// 73.564 us; speedup vs baseline: 1.0664x; 1.0664x over previous
//
#include <hip/hip_runtime.h>

#define SEQ 512
// alpha = log2(e)/sqrt(8); Q is pre-scaled by sqrt(alpha) so score = exp2(q'.q')
#define SQRT_ALPHA     0.71419163f
#define INV_SQRT_ALPHA 1.40018452f

__device__ __forceinline__ float2 pk_fma(float2 a, float2 b, float2 c) {
    return make_float2(fmaf(a.x, b.x, c.x), fmaf(a.y, b.y, c.y));
}

// Kernel 1: analytic quantum feature + attention per (b,h) pair.
// exp[0] = prod_{1..7} cos(x_w+th_w); exp[k] = prod_{0..k} cos(x_w+th_w)
// grid: (64 pairs, 16 chunks of 32 rows), block 256 = 4 waves.
// Each wave: 32 rows x 2 j-slices (lane>>5); 8 slices of 64 j total.
__global__ __launch_bounds__(256) void qattn_kernel(
    const float* __restrict__ x,      // fp32 [8,512,64]
    const float* __restrict__ theta,  // fp32 [8]
    float* __restrict__ ctx)          // fp32 [8,512,8,8] = [4096][64]
{
    __shared__ float Qs[SEQ][8];      // 16 KB, pre-scaled by SQRT_ALPHA
    __shared__ float red[4][32][9];   // 4.5 KB, stride-9 conflict-free

    const int pair  = blockIdx.x;     // b*8 + h
    const int chunk = blockIdx.y;     // 0..15
    const int b = pair >> 3, h = pair & 7;
    const int tid = threadIdx.x;

    float th[8];
    #pragma unroll
    for (int w = 0; w < 8; w++) th[w] = theta[w];

    // Build scaled Q for this pair (512 rows, 2 per thread)
    #pragma unroll
    for (int i = 0; i < 2; i++) {
        int s = i * 256 + tid;
        const float* xp = x + ((size_t)(b * SEQ + s) * 64 + h * 8);
        float4 xa = *reinterpret_cast<const float4*>(xp);
        float4 xb = *reinterpret_cast<const float4*>(xp + 4);
        float c[8];
        c[0] = __cosf(xa.x + th[0]); c[1] = __cosf(xa.y + th[1]);
        c[2] = __cosf(xa.z + th[2]); c[3] = __cosf(xa.w + th[3]);
        c[4] = __cosf(xb.x + th[4]); c[5] = __cosf(xb.y + th[5]);
        c[6] = __cosf(xb.z + th[6]); c[7] = __cosf(xb.w + th[7]);
        float q[8];
        float pre = c[0];
        #pragma unroll
        for (int k = 1; k < 8; k++) { pre *= c[k]; q[k] = pre; }
        float suf = 1.f;
        #pragma unroll
        for (int w = 7; w >= 1; w--) suf *= c[w];
        q[0] = suf;
        float4 qa = make_float4(q[0]*SQRT_ALPHA, q[1]*SQRT_ALPHA, q[2]*SQRT_ALPHA, q[3]*SQRT_ALPHA);
        float4 qb = make_float4(q[4]*SQRT_ALPHA, q[5]*SQRT_ALPHA, q[6]*SQRT_ALPHA, q[7]*SQRT_ALPHA);
        *reinterpret_cast<float4*>(&Qs[s][0]) = qa;
        *reinterpret_cast<float4*>(&Qs[s][4]) = qb;
    }
    __syncthreads();

    const int lane  = tid & 63;
    const int wv    = tid >> 6;             // 0..3
    const int row   = lane & 31;
    const int r     = chunk * 32 + row;     // this lane's row
    const int slice = wv * 2 + (lane >> 5); // 0..7, 64 j each

    float2 qr01 = *reinterpret_cast<const float2*>(&Qs[r][0]);
    float2 qr23 = *reinterpret_cast<const float2*>(&Qs[r][2]);
    float2 qr45 = *reinterpret_cast<const float2*>(&Qs[r][4]);
    float2 qr67 = *reinterpret_cast<const float2*>(&Qs[r][6]);

    float2 a01 = make_float2(0.f, 0.f), a23 = a01, a45 = a01, a67 = a01;
    float l = 0.f;

    // |q'.q'| <= 8*alpha = 4.08 -> exp2 in [2^-4.08, 2^4.08]: no max-sub needed
    const int j0 = slice * 64;
    #pragma unroll 4
    for (int j = j0; j < j0 + 64; j++) {
        float2 u0 = *reinterpret_cast<const float2*>(&Qs[j][0]);
        float2 u1 = *reinterpret_cast<const float2*>(&Qs[j][2]);
        float2 u2 = *reinterpret_cast<const float2*>(&Qs[j][4]);
        float2 u3 = *reinterpret_cast<const float2*>(&Qs[j][6]);
        float2 d = pk_fma(qr01, u0, pk_fma(qr23, u1, pk_fma(qr45, u2,
                   make_float2(qr67.x * u3.x, qr67.y * u3.y))));
        float e = __builtin_amdgcn_exp2f(d.x + d.y);
        l += e;
        float2 ev = make_float2(e, e);
        a01 = pk_fma(ev, u0, a01); a23 = pk_fma(ev, u1, a23);
        a45 = pk_fma(ev, u2, a45); a67 = pk_fma(ev, u3, a67);
    }

    // intra-wave reduce across the two j-halves (lane ^ 32)
    a01.x += __shfl_xor(a01.x, 32); a01.y += __shfl_xor(a01.y, 32);
    a23.x += __shfl_xor(a23.x, 32); a23.y += __shfl_xor(a23.y, 32);
    a45.x += __shfl_xor(a45.x, 32); a45.y += __shfl_xor(a45.y, 32);
    a67.x += __shfl_xor(a67.x, 32); a67.y += __shfl_xor(a67.y, 32);
    l     += __shfl_xor(l, 32);

    if (lane < 32) {
        red[wv][row][0] = a01.x; red[wv][row][1] = a01.y;
        red[wv][row][2] = a23.x; red[wv][row][3] = a23.y;
        red[wv][row][4] = a45.x; red[wv][row][5] = a45.y;
        red[wv][row][6] = a67.x; red[wv][row][7] = a67.y;
        red[wv][row][8] = l;
    }
    __syncthreads();

    // final cross-wave reduce: 256 threads = 32 rows x 8 dims
    {
        const int fr = tid >> 3, fd = tid & 7;
        float v  = red[0][fr][fd] + red[1][fr][fd] + red[2][fr][fd] + red[3][fr][fd];
        float ll = red[0][fr][8]  + red[1][fr][8]  + red[2][fr][8]  + red[3][fr][8];
        float inv = INV_SQRT_ALPHA / ll;   // un-scale acc (q' = sqrt(alpha) q)
        int rr = chunk * 32 + fr;
        ctx[((size_t)(b * SEQ + rr) * 8 + h) * 8 + fd] = v * inv;
    }
}

// Kernel 2: out[t, e] = ctx[t, :] . W_o[e, :] + b_o[e]
// grid 512 x 256; wave handles 2 tokens (all 64 e per token)
__global__ __launch_bounds__(256) void proj_kernel(
    const float* __restrict__ ctx,    // fp32 [4096][64]
    const float* __restrict__ Wo,     // fp32 [64][64]
    const float* __restrict__ bo,     // fp32 [64]
    float* __restrict__ out)          // fp32 [4096][64]
{
    __shared__ float Ws[64][68];      // pitch 68: 16B-aligned rows, conflict-free b128
    const int tid = threadIdx.x;
    #pragma unroll
    for (int i = 0; i < 16; i++) {
        int idx = i * 256 + tid;
        Ws[idx >> 6][idx & 63] = Wo[idx];
    }
    __syncthreads();

    const int e  = tid & 63;
    const int tg = tid >> 6;
    const int t0 = blockIdx.x * 8 + tg * 2;

    const float4* c0 = reinterpret_cast<const float4*>(ctx + (size_t)t0 * 64);
    const float4* c1 = reinterpret_cast<const float4*>(ctx + (size_t)(t0 + 1) * 64);
    float a0 = 0.f, a1 = 0.f;
    #pragma unroll 4
    for (int k4 = 0; k4 < 16; k4++) {
        float4 w  = *reinterpret_cast<const float4*>(&Ws[e][k4 * 4]);
        float4 x0 = c0[k4];            // wave-uniform broadcast
        float4 x1 = c1[k4];
        a0 += x0.x*w.x + x0.y*w.y + x0.z*w.z + x0.w*w.w;
        a1 += x1.x*w.x + x1.y*w.y + x1.z*w.z + x1.w*w.w;
    }
    float bb = bo[e];
    out[(size_t)t0 * 64 + e]       = a0 + bb;
    out[(size_t)(t0 + 1) * 64 + e] = a1 + bb;
}

extern "C" void kernel_launch(void* const* d_in, const int* in_sizes, int n_in,
                              void* d_out, int out_size, void* d_ws, size_t ws_size,
                              hipStream_t stream) {
    const float* x     = (const float*)d_in[0];  // [8,512,64]
    const float* theta = (const float*)d_in[1];  // [8]
    const float* Wo    = (const float*)d_in[2];  // [64,64]
    const float* bo    = (const float*)d_in[3];  // [64]
    float* out = (float*)d_out;                  // [8,512,64]
    float* ctx = (float*)d_ws;                   // 1 MB fp32 scratch

    qattn_kernel<<<dim3(64, 16), 256, 0, stream>>>(x, theta, ctx);
    proj_kernel<<<512, 256, 0, stream>>>(ctx, Wo, bo, out);
}

// Round 4
// 72.834 us; speedup vs baseline: 1.0771x; 1.0100x over previous
//
#include <hip/hip_runtime.h>

#define SEQ 512
// alpha = log2(e)/sqrt(8); Q pre-scaled by sqrt(alpha) so score = exp2(q'.q')
#define SQRT_ALPHA     0.71419163f
#define INV_SQRT_ALPHA 1.40018452f

__device__ __forceinline__ float2 pk_fma(float2 a, float2 b, float2 c) {
    return make_float2(fmaf(a.x, b.x, c.x), fmaf(a.y, b.y, c.y));
}

// Kernel 1: analytic quantum feature + attention per (b,h) pair.
// exp[0] = prod_{1..7} cos(x_w+th_w); exp[k] = prod_{0..k} cos(x_w+th_w)
// grid (64 pairs, 4 chunks of 128 rows), block 512 = 8 waves.
// Wave wv owns j-slice [64wv, 64wv+64); the two half-waves take different j
// (2 distinct LDS addrs/instr = free 2-way); each lane holds 4 rows in regs.
__global__ __launch_bounds__(512) void qattn_kernel(
    const float* __restrict__ x,      // fp32 [8,512,64]
    const float* __restrict__ theta,  // fp32 [8]
    float* __restrict__ ctx)          // fp32 [4096][64]
{
    __shared__ float Qs[SEQ][8];      // 16 KB, pre-scaled by SQRT_ALPHA
    __shared__ float red[8][128][9];  // 36 KB, stride-9 conflict-free

    const int pair  = blockIdx.x;     // b*8 + h
    const int chunk = blockIdx.y;     // 0..3 -> rows [128*chunk, +128)
    const int b = pair >> 3, h = pair & 7;
    const int tid = threadIdx.x;

    float th[8];
    #pragma unroll
    for (int w = 0; w < 8; w++) th[w] = theta[w];

    // Build scaled Q: one row per thread
    {
        const int s = tid;
        const float* xp = x + ((size_t)(b * SEQ + s) * 64 + h * 8);
        float4 xa = *reinterpret_cast<const float4*>(xp);
        float4 xb = *reinterpret_cast<const float4*>(xp + 4);
        float c[8];
        c[0] = __cosf(xa.x + th[0]); c[1] = __cosf(xa.y + th[1]);
        c[2] = __cosf(xa.z + th[2]); c[3] = __cosf(xa.w + th[3]);
        c[4] = __cosf(xb.x + th[4]); c[5] = __cosf(xb.y + th[5]);
        c[6] = __cosf(xb.z + th[6]); c[7] = __cosf(xb.w + th[7]);
        float q[8];
        float pre = c[0];
        #pragma unroll
        for (int k = 1; k < 8; k++) { pre *= c[k]; q[k] = pre; }
        float suf = 1.f;
        #pragma unroll
        for (int w = 7; w >= 1; w--) suf *= c[w];
        q[0] = suf;
        float4 qa = make_float4(q[0]*SQRT_ALPHA, q[1]*SQRT_ALPHA, q[2]*SQRT_ALPHA, q[3]*SQRT_ALPHA);
        float4 qb = make_float4(q[4]*SQRT_ALPHA, q[5]*SQRT_ALPHA, q[6]*SQRT_ALPHA, q[7]*SQRT_ALPHA);
        *reinterpret_cast<float4*>(&Qs[s][0]) = qa;
        *reinterpret_cast<float4*>(&Qs[s][4]) = qb;
    }
    __syncthreads();

    const int lane = tid & 63;
    const int wv   = tid >> 6;        // 0..7
    const int L    = lane & 31;       // row-set index; rows L + {0,32,64,96}

    // 4 rows of Q in registers
    float2 q01[4], q23[4], q45[4], q67[4];
    #pragma unroll
    for (int k = 0; k < 4; k++) {
        const float* qp = &Qs[chunk * 128 + 32 * k + L][0];
        q01[k] = *reinterpret_cast<const float2*>(qp + 0);
        q23[k] = *reinterpret_cast<const float2*>(qp + 2);
        q45[k] = *reinterpret_cast<const float2*>(qp + 4);
        q67[k] = *reinterpret_cast<const float2*>(qp + 6);
    }

    float2 a01[4], a23[4], a45[4], a67[4];
    float l[4];
    #pragma unroll
    for (int k = 0; k < 4; k++) {
        a01[k] = make_float2(0.f, 0.f); a23[k] = a01[k];
        a45[k] = a01[k]; a67[k] = a01[k]; l[k] = 0.f;
    }

    // |q'.q'| <= 8*alpha = 4.08: exp2 safe without max-subtraction
    const float* up = &Qs[wv * 64 + 32 * (lane >> 5)][0];
    #pragma unroll 8
    for (int i = 0; i < 32; i++) {
        float2 u0 = *reinterpret_cast<const float2*>(up + i * 8 + 0);
        float2 u1 = *reinterpret_cast<const float2*>(up + i * 8 + 2);
        float2 u2 = *reinterpret_cast<const float2*>(up + i * 8 + 4);
        float2 u3 = *reinterpret_cast<const float2*>(up + i * 8 + 6);
        #pragma unroll
        for (int k = 0; k < 4; k++) {
            float2 d = pk_fma(q01[k], u0, pk_fma(q23[k], u1, pk_fma(q45[k], u2,
                       make_float2(q67[k].x * u3.x, q67[k].y * u3.y))));
            float e = __builtin_amdgcn_exp2f(d.x + d.y);
            l[k] += e;
            float2 ev = make_float2(e, e);
            a01[k] = pk_fma(ev, u0, a01[k]); a23[k] = pk_fma(ev, u1, a23[k]);
            a45[k] = pk_fma(ev, u2, a45[k]); a67[k] = pk_fma(ev, u3, a67[k]);
        }
    }

    // merge the two j-halves (lane ^ 32)
    #pragma unroll
    for (int k = 0; k < 4; k++) {
        a01[k].x += __shfl_xor(a01[k].x, 32); a01[k].y += __shfl_xor(a01[k].y, 32);
        a23[k].x += __shfl_xor(a23[k].x, 32); a23[k].y += __shfl_xor(a23[k].y, 32);
        a45[k].x += __shfl_xor(a45[k].x, 32); a45[k].y += __shfl_xor(a45[k].y, 32);
        a67[k].x += __shfl_xor(a67[k].x, 32); a67[k].y += __shfl_xor(a67[k].y, 32);
        l[k]     += __shfl_xor(l[k], 32);
    }

    if (lane < 32) {
        #pragma unroll
        for (int k = 0; k < 4; k++) {
            float* rp = &red[wv][32 * k + L][0];
            rp[0] = a01[k].x; rp[1] = a01[k].y; rp[2] = a23[k].x; rp[3] = a23[k].y;
            rp[4] = a45[k].x; rp[5] = a45[k].y; rp[6] = a67[k].x; rp[7] = a67[k].y;
            rp[8] = l[k];
        }
    }
    __syncthreads();

    // final reduce over 8 waves: 1024 (row,d) items over 512 threads
    #pragma unroll
    for (int ii = 0; ii < 2; ii++) {
        int idx = ii * 512 + tid;
        int lr = idx >> 3, d = idx & 7;
        float v = 0.f, ll = 0.f;
        #pragma unroll
        for (int w = 0; w < 8; w++) { v += red[w][lr][d]; ll += red[w][lr][8]; }
        int row = chunk * 128 + lr;
        ctx[(size_t)(b * SEQ + row) * 64 + h * 8 + d] = v * INV_SQRT_ALPHA / ll;
    }
}

// Kernel 2: out[t, e] = ctx[t, :] . W_o[e, :] + b_o[e]
// grid 512 x 256; wave handles 2 tokens (all 64 e per token)
__global__ __launch_bounds__(256) void proj_kernel(
    const float* __restrict__ ctx,    // fp32 [4096][64]
    const float* __restrict__ Wo,     // fp32 [64][64]
    const float* __restrict__ bo,     // fp32 [64]
    float* __restrict__ out)          // fp32 [4096][64]
{
    __shared__ float Ws[64][68];      // pitch 68: 16B-aligned rows, conflict-free b128
    const int tid = threadIdx.x;
    #pragma unroll
    for (int i = 0; i < 16; i++) {
        int idx = i * 256 + tid;
        Ws[idx >> 6][idx & 63] = Wo[idx];
    }
    __syncthreads();

    const int e  = tid & 63;
    const int tg = tid >> 6;
    const int t0 = blockIdx.x * 8 + tg * 2;

    const float4* c0 = reinterpret_cast<const float4*>(ctx + (size_t)t0 * 64);
    const float4* c1 = reinterpret_cast<const float4*>(ctx + (size_t)(t0 + 1) * 64);
    float a0 = 0.f, a1 = 0.f;
    #pragma unroll 4
    for (int k4 = 0; k4 < 16; k4++) {
        float4 w  = *reinterpret_cast<const float4*>(&Ws[e][k4 * 4]);
        float4 x0 = c0[k4];            // wave-uniform broadcast
        float4 x1 = c1[k4];
        a0 += x0.x*w.x + x0.y*w.y + x0.z*w.z + x0.w*w.w;
        a1 += x1.x*w.x + x1.y*w.y + x1.z*w.z + x1.w*w.w;
    }
    float bb = bo[e];
    out[(size_t)t0 * 64 + e]       = a0 + bb;
    out[(size_t)(t0 + 1) * 64 + e] = a1 + bb;
}

extern "C" void kernel_launch(void* const* d_in, const int* in_sizes, int n_in,
                              void* d_out, int out_size, void* d_ws, size_t ws_size,
                              hipStream_t stream) {
    const float* x     = (const float*)d_in[0];  // [8,512,64]
    const float* theta = (const float*)d_in[1];  // [8]
    const float* Wo    = (const float*)d_in[2];  // [64,64]
    const float* bo    = (const float*)d_in[3];  // [64]
    float* out = (float*)d_out;                  // [8,512,64]
    float* ctx = (float*)d_ws;                   // 1 MB fp32 scratch

    qattn_kernel<<<dim3(64, 4), 512, 0, stream>>>(x, theta, ctx);
    proj_kernel<<<512, 256, 0, stream>>>(ctx, Wo, bo, out);
}